// Round 7
// baseline (126.658 us; speedup 1.0000x reference)
//
#include <hip/hip_runtime.h>
#include <stdint.h>
#include <math.h>

// Validated semantics (r17/r18 green): printed reference, fp32 in/out.
//   p[b,j] = mean_h sigmoid(delta/sqrt(32)),
//   delta[j,b,h] = sum_e D_e*(U+V),  D_e = (s_e-mu_s)-(o_e-mu_o)
//   Folded mu: sum_e D*w = sum_e (s-o)*w - ((sum s - sum o)/256)*sum_e w
//   U[h,e,j] = sum_{d in h} QwT[d,j]*Wk[d,e],  QwT = Qp[256+j]@Wq^T
//   V[b,h,e] = sum_{d in h} (Pq[b,d]+bq[d])*Wk[d,e],  Pq = pe[b]@Wq^T
//   new_state[b,e,l<256]=state; l>=256: p*s_l+(1-p)*o_{l-256}
//   atten[b,l,s]: l<256 -> 1 at s=l; else p at s=l, 1-p at s=l+256.
// This round: overlap the P-independent 59 MB of output with the
// latency-bound prologue chain (no events allowed -> intra-kernel mixing,
// compute blocks first in each grid):
//   k_tr  += identity-atten rows l<256 (25.2 MB one-hot, nt stores)
//   k_pro += zero body of atten rows l>=256 (25.2 MB zeros)
//   k_uv  += new_state identity half (state cols 0..255 copy)
//   k_out  = P-dependent only: merge half + 16K scalar diagonal overwrites
//            of the pre-zeroed l>=256 rows (stream order guarantees zeros
//            land first). k_delta unchanged from the 126.6us build.

// d_ws layout (floats) — unchanged
#define WS_P    0        // [32 b][256 j]  sum_h sigmoid
#define WS_QWT  8192     // [256 d][256 j]
#define WS_PQ   73728    // [32 b][256 d]
#define WS_U    81920    // [8 h][256 e][256 j]
#define WS_V    606208   // [32 b][8 h][256 e]
#define WS_QPT  671744   // [256 e][256 j]  QpT[e][j] = Qp[256+j][e]
#define WS_WQT  737280   // [256 e][256 d]  WqT[e][d] = Wq[d][e]
// end 802816 floats = 3.06 MB (ws is 256 MiB per fill WRITE_SIZE)

typedef float vf4 __attribute__((ext_vector_type(4)));
__device__ __forceinline__ void nt_store4(float* p, float x, float y,
                                          float z, float w) {
  vf4 v; v.x = x; v.y = y; v.z = z; v.w = w;
  __builtin_nontemporal_store(v, (vf4*)p);
}

// ---------------------------------------------------------------------------
// K0: [0,128) QpT/WqT transpose; [128,3200) identity-atten rows (l<256).
__global__ void __launch_bounds__(256)
k_tr(const float* __restrict__ Qp, const float* __restrict__ Wq,
     float* __restrict__ ws, float* __restrict__ out) {
  int bid = blockIdx.x, t = threadIdx.x;
  if (bid < 128) {
    __shared__ float tile[32][33];
    const float* src; float* dst; int ti;
    if (bid < 64) { src = Qp + 65536; dst = ws + WS_QPT; ti = bid; }
    else          { src = Wq;         dst = ws + WS_WQT; ti = bid - 64; }
    int tr = ti >> 3, tc = ti & 7;      // row-tile (j/d), col-tile (e)
    int c = t & 31, r0 = t >> 5;
    #pragma unroll
    for (int k = 0; k < 4; ++k) {       // load src tile, coalesced
      int r = r0 + (k << 3);
      tile[r][c] = src[(size_t)(tr * 32 + r) * 256 + tc * 32 + c];
    }
    __syncthreads();
    #pragma unroll
    for (int k = 0; k < 4; ++k) {       // store transposed, coalesced
      int r = r0 + (k << 3);
      dst[(size_t)(tc * 32 + r) * 256 + tr * 32 + c] = tile[c][r];
    }
  } else {                              // atten rows l<256: one-hot at s=l
    int base = (bid - 128) * 512 + t;
    #pragma unroll
    for (int k = 0; k < 2; ++k) {
      int g4 = base + (k << 8);         // 0..1572863
      int row_id = g4 / 192, c = g4 - row_id * 192;
      int b = row_id >> 8, l = row_id & 255;
      float v[4] = {0.f, 0.f, 0.f, 0.f};
      int s0 = c << 2;
      if (l >= s0 && l < s0 + 4) v[l - s0] = 1.0f;
      nt_store4(out + 4194304 + (size_t)((b << 9) + l) * 768 + (c << 2),
                v[0], v[1], v[2], v[3]);
    }
  }
}

// ---------------------------------------------------------------------------
// K1: [0,288) QwT/Pq matvecs; [288,3360) zero body of atten rows l>=256.
__global__ void __launch_bounds__(256)
k_pro(const float* __restrict__ Wq, float* __restrict__ ws,
      float* __restrict__ out) {
  int bid = blockIdx.x, t = threadIdx.x;
  if (bid < 288) {
    __shared__ float lvec[256];
    const float* __restrict__ GT; float* dst;
    if (bid < 256) {                    // QwT[d][j] = sum_e Wq[d][e]*QpT[e][j]
      int d = bid;
      lvec[t] = Wq[(size_t)d * 256 + t];
      GT = ws + WS_QPT; dst = ws + WS_QWT + d * 256;
    } else {                            // Pq[b][d] = sum_e pe[b][e]*WqT[e][d]
      int b = bid - 256;
      int k2 = t & ~1;                  // arange value 2k
      float div = expf((float)k2 * (-9.210340371976184f / 256.f));
      float a = (float)b * div;
      lvec[t] = (t & 1) ? cosf(a) : sinf(a);
      GT = ws + WS_WQT; dst = ws + WS_PQ + b * 256;
    }
    __syncthreads();
    float acc = 0.f;
    #pragma unroll 8
    for (int e = 0; e < 256; ++e)
      acc += lvec[e] * GT[(e << 8) + t];
    dst[t] = acc;
  } else {                              // atten rows l>=256: zero body
    int base = (bid - 288) * 512 + t;
    #pragma unroll
    for (int k = 0; k < 2; ++k) {
      int g4 = base + (k << 8);         // 0..1572863
      int row_id = g4 / 192, c = g4 - row_id * 192;
      int b = row_id >> 8, l = 256 + (row_id & 255);
      nt_store4(out + 4194304 + (size_t)((b << 9) + l) * 768 + (c << 2),
                0.f, 0.f, 0.f, 0.f);    // k_out overwrites the 2 diag vals
    }
  }
}

// ---------------------------------------------------------------------------
// K2: [0,256) U (h, e-tile8); [256,512) V (b,h); [512,1536) new_state
// identity half (state cols 0..255 copy).
__global__ void __launch_bounds__(256)
k_uv(const float* __restrict__ Wk, const float* __restrict__ bq,
     const float* __restrict__ state, float* __restrict__ ws,
     float* __restrict__ out) {
  int bid = blockIdx.x, t = threadIdx.x;
  if (bid < 256) {
    int h = bid >> 5, e0 = (bid & 31) << 3;
    __shared__ float wk_s[32][9];       // [d in h][e0..e0+7], +1 pad
    {
      int d = t >> 3, i = t & 7;        // 256 threads cover 32x8
      wk_s[d][i] = Wk[(size_t)(h * 32 + d) * 256 + e0 + i];
    }
    __syncthreads();
    float acc[8] = {0.f, 0.f, 0.f, 0.f, 0.f, 0.f, 0.f, 0.f};
    const float* __restrict__ Qw = ws + WS_QWT + t;
    #pragma unroll 4
    for (int d = 0; d < 32; ++d) {
      float q = Qw[((h << 5) + d) << 8];  // coalesced; wk_s broadcast
      #pragma unroll
      for (int i = 0; i < 8; ++i) acc[i] += wk_s[d][i] * q;
    }
    float* Uh = ws + WS_U + (h << 16) + (size_t)e0 * 256;
    #pragma unroll
    for (int i = 0; i < 8; ++i) Uh[(size_t)i * 256 + t] = acc[i];
  } else if (bid < 512) {
    int idx = bid - 256, b = idx >> 3, h = idx & 7;
    float acc = 0.f;
#pragma unroll 8
    for (int dd = 0; dd < 32; ++dd) {
      int d = h * 32 + dd;
      acc += (ws[WS_PQ + b * 256 + d] + bq[d]) * Wk[(size_t)d * 256 + t];
    }
    ws[WS_V + ((b << 3) + h) * 256 + t] = acc;
  } else {                              // new_state[b,e,0..255] = state
    int base = (bid - 512) * 512 + t;
    #pragma unroll
    for (int k = 0; k < 2; ++k) {
      int g4 = base + (k << 8);         // 0..524287
      int row = g4 >> 6, c = g4 & 63;   // row = b*256+e, cols l = 4c..4c+3
      float4 sv = ((const float4*)state)[(size_t)row * 128 + c];
      nt_store4(out + (size_t)row * 512 + (c << 2), sv.x, sv.y, sv.z, sv.w);
    }
  }
}

// ---------------------------------------------------------------------------
// K3: delta. 256 blocks = (b, j-tile of 32) x 256 threads. (unchanged)
__global__ void __launch_bounds__(256)
k_delta(const float* __restrict__ state, const float* __restrict__ obs,
        float* __restrict__ ws) {
  int b = blockIdx.x >> 3, jt = (blockIdx.x & 7) << 5;
  int t = threadIdx.x;
  __shared__ float Xs[256][33];         // X[e][j], +1 pad -> <=2-way (free)
  __shared__ float Vs[2048];            // V[b][h][e] slice
  __shared__ float pd[8][8][32];        // [eg][h][j] partial sum X*w
  __shared__ float pw[8][8][32];        // [eg][h][j] partial sum w
  __shared__ float px[8][32];           // [eg][j]    partial sum X (reused)
  {                                     // stage: (es 0..31, jq 0..7) float4
    int es = t >> 3, jq = t & 7;
    const float* sp = state + (size_t)b * 131072 + 256 + jt + (jq << 2);
    const float* op = obs   + (size_t)b * 65536  + jt + (jq << 2);
    #pragma unroll
    for (int k = 0; k < 8; ++k) {
      int e = es + (k << 5);
      float4 s4 = *(const float4*)(sp + (size_t)e * 512);
      float4 o4 = *(const float4*)(op + (size_t)e * 256);
      float* xr = &Xs[e][jq << 2];
      xr[0] = s4.x - o4.x; xr[1] = s4.y - o4.y;
      xr[2] = s4.z - o4.z; xr[3] = s4.w - o4.w;
    }
    for (int i = t; i < 2048; i += 256) Vs[i] = ws[WS_V + (b << 11) + i];
  }
  __syncthreads();
  int j = t & 31, eg = t >> 5, e0 = eg << 5;
  {                                     // a_x partial (h-independent)
    float ax = 0.f;
    #pragma unroll
    for (int ei = 0; ei < 32; ++ei) ax += Xs[e0 + ei][j];
    px[eg][j] = ax;
  }
  const float* __restrict__ Ub = ws + WS_U + jt + j;
  #pragma unroll
  for (int h = 0; h < 8; ++h) {
    float dacc = 0.f, wacc = 0.f;
    const float* __restrict__ Uh = Ub + (h << 16) + (e0 << 8);
    const float* __restrict__ Vh = Vs + (h << 8) + e0;
    #pragma unroll 16
    for (int ei = 0; ei < 32; ++ei) {
      float w = Uh[ei << 8] + Vh[ei];
      dacc += Xs[e0 + ei][j] * w;
      wacc += w;
    }
    pd[eg][h][j] = dacc;
    pw[eg][h][j] = wacc;
  }
  __syncthreads();
  int h2 = t >> 5, j2 = t & 31;         // thread -> (h, j) for the merge
  float D = 0.f, W = 0.f, X = 0.f;
  #pragma unroll
  for (int g = 0; g < 8; ++g) {
    D += pd[g][h2][j2];
    W += pw[g][h2][j2];
    X += px[g][j2];
  }
  float delta = D - X * (1.f / 256.f) * W;
  float sig = 1.f / (1.f + __expf(-delta * 0.17677669529663687f)); // /sqrt(32)
  __syncthreads();
  px[h2][j2] = sig;                     // reuse px as [h][j] sigmoid buffer
  __syncthreads();
  if (t < 32) {
    float acc = 0.f;
    #pragma unroll
    for (int h = 0; h < 8; ++h) acc += px[h][t];
    ws[WS_P + (b << 8) + jt + t] = acc; // sum_h; k_out applies *0.125
  }
}

// ---------------------------------------------------------------------------
// K4: P-dependent output only. [0,2048) new_state merge half (cols 256..511);
// [2048,2080) sparse diagonal overwrites of the pre-zeroed atten rows.
__global__ void __launch_bounds__(256)
k_out(const float* __restrict__ state, const float* __restrict__ obs,
      const float* __restrict__ ws, float* __restrict__ out) {
  int bid = blockIdx.x, t = threadIdx.x;
  if (bid < 2048) {                     // merge: 4 rows/block, 64 f4 each
    int row = (bid << 2) | (t >> 6);    // row = b*256 + e
    int c = t & 63;                     // f4 index in upper half
    int b = row >> 8;
    float4 sv = ((const float4*)(state + (size_t)row * 512))[64 + c];
    float4 ov = ((const float4*)(obs + (size_t)row * 256))[c];
    float4 p4 = ((const float4*)(ws + WS_P + b * 256))[c];
    p4.x *= 0.125f; p4.y *= 0.125f; p4.z *= 0.125f; p4.w *= 0.125f;
    nt_store4(out + (size_t)row * 512 + 256 + (c << 2),
              p4.x * sv.x + (1.f - p4.x) * ov.x,
              p4.y * sv.y + (1.f - p4.y) * ov.y,
              p4.z * sv.z + (1.f - p4.z) * ov.z,
              p4.w * sv.w + (1.f - p4.w) * ov.w);
  } else {                              // atten diag: (b, l=256+j)
    int idx = ((bid - 2048) << 8) + t;  // 0..8191
    int b = idx >> 8, j = idx & 255;
    float p = ws[WS_P + (b << 8) + j] * 0.125f;
    size_t r = 4194304 + (size_t)((b << 9) + 256 + j) * 768;
    out[r + 256 + j] = p;               // s = l
    out[r + 512 + j] = 1.f - p;         // s = l + 256
  }
}

extern "C" void kernel_launch(void* const* d_in, const int* in_sizes, int n_in,
                              void* d_out, int out_size, void* d_ws, size_t ws_size,
                              hipStream_t stream) {
  const float *state = nullptr, *obs = nullptr, *Qp = nullptr;
  const float *Wq = nullptr, *Wk = nullptr, *bq = nullptr, *bk = nullptr;
  for (int i = 0; i < n_in; ++i) {
    int s = in_sizes[i];
    const float* p = (const float*)d_in[i];
    if      (s == 4194304) state = p;
    else if (s == 2097152) obs = p;
    else if (s == 131072)  Qp = p;
    else if (s == 65536)   { if (!Wq) Wq = p; else Wk = p; }
    else if (s == 256)     { if (!bq) bq = p; else bk = p; }
  }
  (void)bk;                             // cancels in the 2-way softmax
  float* out = (float*)d_out;
  float* ws  = (float*)d_ws;

  k_tr   <<<3200, 256, 0, stream>>>(Qp, Wq, ws, out);
  k_pro  <<<3360, 256, 0, stream>>>(Wq, ws, out);
  k_uv   <<<1536, 256, 0, stream>>>(Wk, bq, state, ws, out);
  k_delta<<<256,  256, 0, stream>>>(state, obs, ws);
  k_out  <<<2080, 256, 0, stream>>>(state, obs, ws, out);
}